// Round 9
// baseline (332.993 us; speedup 1.0000x reference)
//
#include <hip/hip_runtime.h>

#define BB 64
#define NN 128
#define INF_ 5
#define LATD 3
#define HIDD 64

__device__ __forceinline__ float bflo(unsigned u) { return __uint_as_float(u << 16); }
__device__ __forceinline__ float bfhi(unsigned u) { return __uint_as_float(u & 0xffff0000u); }
__device__ __forceinline__ unsigned bfpack(float a, float b) {
    unsigned ua = __float_as_uint(a), ub = __float_as_uint(b);
    unsigned ra = (ua + 0x7fffu + ((ua >> 16) & 1u)) >> 16;   // RNE
    unsigned rb = (ub + 0x7fffu + ((ub >> 16) & 1u)) >> 16;
    return ra | (rb << 16);
}
__device__ __forceinline__ float rlane(float v, int l) {      // uniform-index lane read, scalar path
    return __int_as_float(__builtin_amdgcn_readlane(__float_as_int(v), l));
}

// ---------------------------------------------------------------------------
// Encoder (f64, expressions unchanged across rounds -> adjacency bits stable).
// Also zeroes o5/o6 (replaces the memset dispatch). Grid (B,4).
// ---------------------------------------------------------------------------
__global__ __launch_bounds__(256) void enc_kernel(
    const float* __restrict__ batch,
    const float* __restrict__ w1, const float* __restrict__ b1,
    const float* __restrict__ w2, const float* __restrict__ b2,
    const float* __restrict__ w3, const float* __restrict__ b3,
    double* __restrict__ aos,
    float* __restrict__ o0, float* __restrict__ o1, float* __restrict__ o4,
    float* __restrict__ o5)
{
    const int b = blockIdx.x;
    const int n0 = blockIdx.y * 32;
    const int tid = threadIdx.x;
    const int w = tid >> 6, lane = tid & 63;

    // zero adj + edge_dist (contiguous 8 MB region starting at o5)
    {
        const int blk = blockIdx.x * 4 + blockIdx.y;      // 0..255
        float4* z = (float4*)o5 + (size_t)blk * 2048;
        float4 zero = make_float4(0.f, 0.f, 0.f, 0.f);
        for (int q = tid; q < 2048; q += 256) z[q] = zero;
    }

    __shared__ double xs[32][6];
    __shared__ double w1s[INF_][HIDD];
    __shared__ float  w2s[HIDD * HIDD];
    __shared__ double w3s[HIDD][LATD];
    __shared__ double b1s[HIDD], b2s[HIDD], b3s[LATD];

    for (int idx = tid; idx < 32 * INF_; idx += 256) {
        int n = idx / INF_, c = idx % INF_;
        float v = batch[((size_t)b * NN + n0 + n) * INF_ + c];
        xs[n][c] = (double)v;
        if (c < 4) o0[((size_t)b * NN + n0 + n) * 4 + c] = v;
        else       o1[(size_t)b * NN + n0 + n] = v;
    }
    for (int idx = tid; idx < INF_ * HIDD; idx += 256)
        w1s[idx / HIDD][idx % HIDD] = (double)w1[idx];
    for (int idx = tid; idx < HIDD * HIDD; idx += 256)
        w2s[idx] = w2[idx];
    for (int idx = tid; idx < HIDD * LATD; idx += 256)
        w3s[idx / LATD][idx % LATD] = (double)w3[idx];
    if (tid < HIDD) {
        b1s[tid] = (double)b1[tid];
        b2s[tid] = (double)b2[tid];
    }
    if (tid < LATD) b3s[tid] = (double)b3[tid];
    __syncthreads();

    for (int r = 0; r < 8; ++r) {
        const int nl = w * 8 + r;
        const int n = n0 + nl;
        double h1v = b1s[lane];
        for (int k = 0; k < INF_; ++k) h1v += xs[nl][k] * w1s[k][lane];
        h1v = fmax(h1v, 0.0);
        double h2v = b2s[lane];
        for (int k = 0; k < HIDD; ++k) {
            double h1k = __shfl(h1v, k, 64);
            h2v += h1k * (double)w2s[k * HIDD + lane];
        }
        h2v = fmax(h2v, 0.0);
        double l0 = h2v * w3s[lane][0];
        double l1 = h2v * w3s[lane][1];
        double l2 = h2v * w3s[lane][2];
        for (int o = 32; o >= 1; o >>= 1) {
            l0 += __shfl_xor(l0, o, 64);
            l1 += __shfl_xor(l1, o, 64);
            l2 += __shfl_xor(l2, o, 64);
        }
        l0 += b3s[0]; l1 += b3s[1]; l2 += b3s[2];
        if (lane == 0) {
            double* A = aos + ((size_t)b * NN + n) * 4;
            A[0] = l0; A[1] = l1; A[2] = l2;
            A[3] = l0 * l0 + l1 * l1 + l2 * l2;
        }
        if (lane < LATD) {
            double lv = (lane == 0) ? l0 : ((lane == 1) ? l1 : l2);
            o4[((size_t)b * NN + n) * LATD + lane] = (float)lv;
        }
    }
}

// ---------------------------------------------------------------------------
// Gabriel v5: wave = pair stream, lane = witness k (registers), identity
// d2-r2 == (pk-pi).(pk-pj). Occupancy 2x over r8: each wave takes the
// j-parity half of a balanced row pair (v, 126-v) -> 2048 blocks, 32
// waves/CU (r8: 30% occupancy, VALU idle half the time).
// ---------------------------------------------------------------------------
__global__ __launch_bounds__(256) void gabriel_kernel(
    const double* __restrict__ aos,
    float* __restrict__ o5, float* __restrict__ o6)
{
    const int b = blockIdx.y;
    const int w = threadIdx.x >> 6, lane = threadIdx.x & 63;
    const int u = blockIdx.x * 4 + w;          // 0..127
    const int v = u >> 1, par = u & 1;

    __shared__ double4 Ps[NN];                 // {x,y,z,pk2}, 4 KB
    const double2* src = (const double2*)(aos + (size_t)b * NN * 4);
    double2* dst = (double2*)Ps;
    for (int idx = threadIdx.x; idx < NN * 2; idx += 256) dst[idx] = src[idx];
    __syncthreads();

    const double4 A  = Ps[lane];
    const double4 Bq = Ps[lane + 64];

    for (int half = 0; half < 2; ++half) {
        const int i = (half == 0) ? v : 126 - v;
        if (half == 1 && i == v) break;        // v==63: single row
        const int jstart = (half == 0) ? (v + 1) : (127 - v);
        const int j0 = jstart + ((jstart ^ par) & 1);
        const double4 pi = Ps[i];
        const double aix = A.x - pi.x,  aiy = A.y - pi.y,  aiz = A.z - pi.z;
        const double bix = Bq.x - pi.x, biy = Bq.y - pi.y, biz = Bq.z - pi.z;
        const bool mA = (lane != i), mB = (lane + 64 != i);
        for (int j = j0; j < NN; j += 2) {
            double4 pj = Ps[j];
            double ajx = A.x - pj.x,  ajy = A.y - pj.y,  ajz = A.z - pj.z;
            double bjx = Bq.x - pj.x, bjy = Bq.y - pj.y, bjz = Bq.z - pj.z;
            double dA = aix * ajx + aiy * ajy + aiz * ajz;   // = d2 - r2 (exact algebra)
            double dB = bix * bjx + biy * bjy + biz * bjz;
            bool tA = (dA < 0.0) && mA && (lane != j);
            bool tB = (dB < 0.0) && mB && (lane + 64 != j);
            if (!__any(tA || tB)) {
                if (lane == 0) {
                    double dx = pi.x - pj.x, dy = pi.y - pj.y, dz = pi.z - pj.z;
                    float d = (float)sqrt(dx * dx + dy * dy + dz * dz);
                    size_t ij = ((size_t)b * NN + i) * NN + j;
                    size_t ji = ((size_t)b * NN + j) * NN + i;
                    o5[ij] = 1.0f; o5[ji] = 1.0f;
                    o6[ij] = d;    o6[ji] = d;
                }
            }
        }
    }
}

// ---------------------------------------------------------------------------
// Linear stage -> PACKED bf16x2 hl/hr scratch (halves store + attn-load
// traffic; precision margin is ~300x). Grid (BB*4 [, layers]); lane = h;
// pack pairs via one shfl_xor per node.
// ---------------------------------------------------------------------------
template <int CIN>
__device__ __forceinline__ void lin_body(
    int b, int n0, const float* __restrict__ xin, const float* __restrict__ latf,
    const float* __restrict__ wl, const float* __restrict__ bl,
    const float* __restrict__ wr, const float* __restrict__ br,
    unsigned* __restrict__ hlp, unsigned* __restrict__ hrp,
    float4* xs4, int tid)
{
    float* xsh = (float*)xs4;
    if constexpr (CIN == 64) {
        const float4* src = (const float4*)(xin + ((size_t)b * NN + n0) * HIDD);
        for (int idx = tid; idx < 32 * 16; idx += 256) xs4[idx] = src[idx];
    } else {
        if (tid < 32) xsh[tid] = latf[((size_t)b * NN + n0 + tid) * LATD + 2];
    }
    __syncthreads();

    const int w = tid >> 6, lane = tid & 63;
    float wc[CIN];
    #pragma unroll
    for (int k = 0; k < CIN; ++k) wc[k] = wl[k * HIDD + lane];
    float bv = bl[lane];
    for (int m = 0; m < 8; ++m) {
        int nl = w * 8 + m;
        float acc = bv;
        if constexpr (CIN == 64) {
            #pragma unroll
            for (int t = 0; t < 16; ++t) {
                float4 q = xs4[nl * 16 + t];
                acc = fmaf(q.x, wc[4 * t + 0], acc);
                acc = fmaf(q.y, wc[4 * t + 1], acc);
                acc = fmaf(q.z, wc[4 * t + 2], acc);
                acc = fmaf(q.w, wc[4 * t + 3], acc);
            }
        } else acc = fmaf(xsh[nl], wc[0], acc);
        float partner = __shfl_xor(acc, 1, 64);
        if ((lane & 1) == 0)
            hlp[((size_t)b * NN + n0 + nl) * 32 + (lane >> 1)] = bfpack(acc, partner);
    }
    #pragma unroll
    for (int k = 0; k < CIN; ++k) wc[k] = wr[k * HIDD + lane];
    bv = br[lane];
    for (int m = 0; m < 8; ++m) {
        int nl = w * 8 + m;
        float acc = bv;
        if constexpr (CIN == 64) {
            #pragma unroll
            for (int t = 0; t < 16; ++t) {
                float4 q = xs4[nl * 16 + t];
                acc = fmaf(q.x, wc[4 * t + 0], acc);
                acc = fmaf(q.y, wc[4 * t + 1], acc);
                acc = fmaf(q.z, wc[4 * t + 2], acc);
                acc = fmaf(q.w, wc[4 * t + 3], acc);
            }
        } else acc = fmaf(xsh[nl], wc[0], acc);
        float partner = __shfl_xor(acc, 1, 64);
        if ((lane & 1) == 0)
            hrp[((size_t)b * NN + n0 + nl) * 32 + (lane >> 1)] = bfpack(acc, partner);
    }
}

template <int CIN>
__global__ __launch_bounds__(256) void lin_kernel(
    const float* __restrict__ xin, const float* __restrict__ latf,
    const float* __restrict__ wl, const float* __restrict__ bl,
    const float* __restrict__ wr, const float* __restrict__ br,
    unsigned* __restrict__ hlp, unsigned* __restrict__ hrp)
{
    __shared__ float4 xs4[(CIN == 64) ? 32 * 16 : 8];
    lin_body<CIN>(blockIdx.x >> 2, (blockIdx.x & 3) << 5, xin, latf,
                  wl, bl, wr, br, hlp, hrp, xs4, threadIdx.x);
}

// layers 3&4 fused: y=0 -> (wl3,wr3)->hl3p/hr3p ; y=1 -> (wl4,wr4)->hlp/hrp
__global__ __launch_bounds__(256) void lin34_kernel(
    const float* __restrict__ xin,
    const float* __restrict__ wl3, const float* __restrict__ bl3,
    const float* __restrict__ wr3, const float* __restrict__ br3,
    const float* __restrict__ wl4, const float* __restrict__ bl4,
    const float* __restrict__ wr4, const float* __restrict__ br4,
    unsigned* __restrict__ hl3p, unsigned* __restrict__ hr3p,
    unsigned* __restrict__ hl4p, unsigned* __restrict__ hr4p)
{
    __shared__ float4 xs4[32 * 16];
    const int b = blockIdx.x >> 2, n0 = (blockIdx.x & 3) << 5;
    if (blockIdx.y == 0)
        lin_body<64>(b, n0, xin, nullptr, wl3, bl3, wr3, br3, hl3p, hr3p, xs4, threadIdx.x);
    else
        lin_body<64>(b, n0, xin, nullptr, wl4, bl4, wr4, br4, hl4p, hr4p, xs4, threadIdx.x);
}

// ---------------------------------------------------------------------------
// Attention, LDS-minimized (r8 was LDS-port bound: ~427 LDS insts/wave).
// Only hls lives in LDS (~35 KB). hr row / att / softmax weights stay in
// per-lane REGISTERS; all uniform-index accesses use v_readlane (scalar
// path) with fully unrolled loops. No as4, no barriers after staging.
// ---------------------------------------------------------------------------
template <int C>
__device__ __forceinline__ void attn_body(
    int b, int i0, float* hls, int tid,
    const unsigned* __restrict__ hlp, const unsigned* __restrict__ hrp,
    const float* __restrict__ att, const float* __restrict__ bias,
    const float* __restrict__ adjf, const float* __restrict__ latf,
    const float* __restrict__ skw, const float* __restrict__ skb,
    float* __restrict__ xout,
    const float* __restrict__ head_w, const float* __restrict__ head_b,
    float* __restrict__ head_out)
{
    const int w = tid >> 6, lane = tid & 63;

    // stage hls (unpack bf16x2 -> f32, stride 68)
    {
        const uint4* src = (const uint4*)(hlp + (size_t)b * NN * 32);
        for (int idx = tid; idx < NN * 8; idx += 256) {
            int j = idx >> 3, q = idx & 7;
            uint4 u4 = src[idx];
            *(float4*)&hls[j * 68 + 8 * q] =
                make_float4(bflo(u4.x), bfhi(u4.x), bflo(u4.y), bfhi(u4.y));
            *(float4*)&hls[j * 68 + 8 * q + 4] =
                make_float4(bflo(u4.z), bfhi(u4.z), bflo(u4.w), bfhi(u4.w));
        }
    }
    // register-resident params
    float attv = att[lane];
    float bsv  = bias[lane];
    float hrv[4];
    #pragma unroll
    for (int r = 0; r < 4; ++r) {
        unsigned u = hrp[((size_t)b * NN + i0 + w * 4 + r) * 32 + (lane >> 1)];
        hrv[r] = (lane & 1) ? bfhi(u) : bflo(u);
    }
    float sw0 = 0.f, sw1 = 0.f, sw2 = 0.f, sbv = 0.f;
    if (skw != nullptr) {
        sw0 = skw[lane]; sw1 = skw[64 + lane]; sw2 = skw[128 + lane];
        sbv = skb[lane];
    }
    __syncthreads();

    // hoist this lane's two hl rows (b128, stride 17 float4 -> 2-way, free)
    float h0[HIDD], h1[HIDD];
    #pragma unroll
    for (int t = 0; t < 16; ++t) {
        float4 q0 = *(const float4*)&hls[lane * 68 + 4 * t];
        float4 q1 = *(const float4*)&hls[(lane + 64) * 68 + 4 * t];
        h0[4 * t + 0] = q0.x; h0[4 * t + 1] = q0.y; h0[4 * t + 2] = q0.z; h0[4 * t + 3] = q0.w;
        h1[4 * t + 0] = q1.x; h1[4 * t + 1] = q1.y; h1[4 * t + 2] = q1.z; h1[4 * t + 3] = q1.w;
    }

    // Phase A: 4 softmaxes; hr/att via readlane (scalar), zero LDS traffic
    float a0[4], a1[4];
    #pragma unroll
    for (int r = 0; r < 4; ++r) {
        const int i = i0 + w * 4 + r;
        float acc0 = 0.f, acc1 = 0.f;
        #pragma unroll
        for (int h = 0; h < HIDD; ++h) {
            float sh = rlane(hrv[r], h);
            float av = rlane(attv, h);
            float e0 = sh + h0[h]; e0 = (e0 > 0.f) ? e0 : 0.2f * e0;
            float e1 = sh + h1[h]; e1 = (e1 > 0.f) ? e1 : 0.2f * e1;
            acc0 = fmaf(av, e0, acc0);
            acc1 = fmaf(av, e1, acc1);
        }
        const float* arow = adjf + ((size_t)b * NN + i) * NN;
        bool ad0 = (arow[lane] != 0.f)      || (lane == i);
        bool ad1 = (arow[lane + 64] != 0.f) || (lane + 64 == i);
        float s0 = ad0 ? acc0 : -1e30f;
        float s1 = ad1 ? acc1 : -1e30f;
        float mxv = fmaxf(s0, s1);
        for (int o = 32; o >= 1; o >>= 1) mxv = fmaxf(mxv, __shfl_xor(mxv, o, 64));
        float e0 = __expf(s0 - mxv), e1 = __expf(s1 - mxv);
        float sm = e0 + e1;
        for (int o = 32; o >= 1; o >>= 1) sm += __shfl_xor(sm, o, 64);
        float inv = 1.f / sm;
        a0[r] = e0 * inv;
        a1[r] = e1 * inv;
    }

    // Phase B: joint aggregation; a-values via readlane -> 1 LDS read per j
    float acc[4] = {0.f, 0.f, 0.f, 0.f};
    #pragma unroll
    for (int j = 0; j < 64; ++j) {
        float hv = hls[j * 68 + lane];
        #pragma unroll
        for (int r = 0; r < 4; ++r) acc[r] = fmaf(rlane(a0[r], j), hv, acc[r]);
    }
    #pragma unroll
    for (int j = 0; j < 64; ++j) {
        float hv = hls[(j + 64) * 68 + lane];
        #pragma unroll
        for (int r = 0; r < 4; ++r) acc[r] = fmaf(rlane(a1[r], j), hv, acc[r]);
    }

    // epilogue
    #pragma unroll
    for (int r = 0; r < 4; ++r) {
        const int il = w * 4 + r, i = i0 + il;
        float out = acc[r] + bsv;
        if (skw != nullptr) {
            const float* lr = latf + ((size_t)b * NN + i) * LATD;
            float l0v = lr[0], l1v = lr[1], l2v = lr[2];
            float sk = sbv;
            sk = fmaf(l0v, sw0, sk);
            sk = fmaf(l1v, sw1, sk);
            sk = fmaf(l2v, sw2, sk);
            out += 0.1f * sk;
        }
        out = fmaxf(out, 0.f);
        if constexpr (C == 0) {
            xout[((size_t)b * NN + i) * HIDD + lane] = out;
        } else {
            float hv[C > 0 ? C : 1];
            #pragma unroll
            for (int c = 0; c < C; ++c) {
                float vv = out * head_w[lane * C + c];
                for (int o = 32; o >= 1; o >>= 1) vv += __shfl_xor(vv, o, 64);
                hv[c] = vv + head_b[c];
            }
            if (lane == 0)
                for (int c = 0; c < C; ++c)
                    head_out[((size_t)b * NN + i) * C + c] = hv[c];
        }
    }
}

__global__ __launch_bounds__(256, 2) void attn12_kernel(
    const unsigned* __restrict__ hlp, const unsigned* __restrict__ hrp,
    const float* __restrict__ att, const float* __restrict__ bias,
    const float* __restrict__ adjf, float* __restrict__ xout)
{
    __shared__ __align__(16) float hls[NN * 68];
    attn_body<0>(blockIdx.x >> 3, (blockIdx.x & 7) << 4, hls, threadIdx.x,
                 hlp, hrp, att, bias, adjf, nullptr, nullptr, nullptr,
                 xout, nullptr, nullptr, nullptr);
}

__global__ __launch_bounds__(256, 2) void attn34_kernel(
    const unsigned* __restrict__ hl3p, const unsigned* __restrict__ hr3p,
    const unsigned* __restrict__ hl4p, const unsigned* __restrict__ hr4p,
    const float* __restrict__ att3, const float* __restrict__ b3,
    const float* __restrict__ att4, const float* __restrict__ b4,
    const float* __restrict__ adjf, const float* __restrict__ latf,
    const float* __restrict__ skw, const float* __restrict__ skb,
    const float* __restrict__ lab_w, const float* __restrict__ lab_b, float* __restrict__ o2,
    const float* __restrict__ val_w, const float* __restrict__ val_b, float* __restrict__ o3)
{
    __shared__ __align__(16) float hls[NN * 68];
    const int b = blockIdx.x >> 3, i0 = (blockIdx.x & 7) << 4;
    if (blockIdx.y == 0)
        attn_body<4>(b, i0, hls, threadIdx.x, hl3p, hr3p, att3, b3, adjf, latf,
                     skw, skb, nullptr, lab_w, lab_b, o2);
    else
        attn_body<1>(b, i0, hls, threadIdx.x, hl4p, hr4p, att4, b4, adjf, latf,
                     skw, skb, nullptr, val_w, val_b, o3);
}

// ---------------------------------------------------------------------------
extern "C" void kernel_launch(void* const* d_in, const int* in_sizes, int n_in,
                              void* d_out, int out_size, void* d_ws, size_t ws_size,
                              hipStream_t stream)
{
    const float* batch  = (const float*)d_in[0];
    const float* enc_w1 = (const float*)d_in[1];
    const float* enc_b1 = (const float*)d_in[2];
    const float* enc_w2 = (const float*)d_in[3];
    const float* enc_b2 = (const float*)d_in[4];
    const float* enc_w3 = (const float*)d_in[5];
    const float* enc_b3 = (const float*)d_in[6];
    const float* g_wl[4]  = {(const float*)d_in[7],  (const float*)d_in[13], (const float*)d_in[19], (const float*)d_in[25]};
    const float* g_bl[4]  = {(const float*)d_in[8],  (const float*)d_in[14], (const float*)d_in[20], (const float*)d_in[26]};
    const float* g_wr[4]  = {(const float*)d_in[9],  (const float*)d_in[15], (const float*)d_in[21], (const float*)d_in[27]};
    const float* g_br[4]  = {(const float*)d_in[10], (const float*)d_in[16], (const float*)d_in[22], (const float*)d_in[28]};
    const float* g_att[4] = {(const float*)d_in[11], (const float*)d_in[17], (const float*)d_in[23], (const float*)d_in[29]};
    const float* g_b[4]   = {(const float*)d_in[12], (const float*)d_in[18], (const float*)d_in[24], (const float*)d_in[30]};
    const float* lab_w = (const float*)d_in[31];
    const float* lab_b = (const float*)d_in[32];
    const float* val_w = (const float*)d_in[33];
    const float* val_b = (const float*)d_in[34];
    const float* skw   = (const float*)d_in[35];
    const float* skb   = (const float*)d_in[36];

    float* out = (float*)d_out;
    float* o0 = out;            // batch[:,:,:4]   32768
    float* o1 = out + 32768;    // batch[:,:,4:5]   8192
    float* o2 = out + 40960;    // logits          32768
    float* o3 = out + 73728;    // values           8192
    float* o4 = out + 81920;    // latent          24576  (doubles as latf)
    float* o5 = out + 106496;   // adj           1048576
    float* o6 = out + 1155072;  // edge_dist     1048576

    // Scratch: 8.25 MB (hl/hr packed bf16x2 -> 1 MB each).
    char* p = (char*)d_ws;
    auto carve = [&](size_t bytes) { void* r = (void*)p; p += (bytes + 255) & ~(size_t)255; return r; };
    double*   aos  = (double*)  carve((size_t)BB * NN * 4 * 8);      // 256 KB
    float*    xA   = (float*)   carve((size_t)BB * NN * HIDD * 4);   // 2 MB
    float*    xB   = (float*)   carve((size_t)BB * NN * HIDD * 4);   // 2 MB
    unsigned* hlp  = (unsigned*)carve((size_t)BB * NN * 32 * 4);     // 1 MB
    unsigned* hrp  = (unsigned*)carve((size_t)BB * NN * 32 * 4);     // 1 MB
    unsigned* hl3p = (unsigned*)carve((size_t)BB * NN * 32 * 4);     // 1 MB
    unsigned* hr3p = (unsigned*)carve((size_t)BB * NN * 32 * 4);     // 1 MB

    enc_kernel<<<dim3(BB, 4), 256, 0, stream>>>(batch, enc_w1, enc_b1, enc_w2, enc_b2,
                                                enc_w3, enc_b3, aos, o0, o1, o4, o5);
    gabriel_kernel<<<dim3(32, BB), 256, 0, stream>>>(aos, o5, o6);

    // layer 1 (Cin=1, x0 = latent[...,2]) -> xA
    lin_kernel<1><<<BB * 4, 256, 0, stream>>>(nullptr, o4, g_wl[0], g_bl[0], g_wr[0], g_br[0], hlp, hrp);
    attn12_kernel<<<BB * 8, 256, 0, stream>>>(hlp, hrp, g_att[0], g_b[0], o5, xA);
    // layer 2 -> xB
    lin_kernel<64><<<BB * 4, 256, 0, stream>>>(xA, nullptr, g_wl[1], g_bl[1], g_wr[1], g_br[1], hlp, hrp);
    attn12_kernel<<<BB * 8, 256, 0, stream>>>(hlp, hrp, g_att[1], g_b[1], o5, xB);
    // layers 3+4 fused (both read xB)
    lin34_kernel<<<dim3(BB * 4, 2), 256, 0, stream>>>(xB,
        g_wl[2], g_bl[2], g_wr[2], g_br[2], g_wl[3], g_bl[3], g_wr[3], g_br[3],
        hl3p, hr3p, hlp, hrp);
    attn34_kernel<<<dim3(BB * 8, 2), 256, 0, stream>>>(hl3p, hr3p, hlp, hrp,
        g_att[2], g_b[2], g_att[3], g_b[3], o5, o4, skw, skb,
        lab_w, lab_b, o2, val_w, val_b, o3);
}

// Round 10
// 304.879 us; speedup vs baseline: 1.0922x; 1.0922x over previous
//
#include <hip/hip_runtime.h>

#define BB 64
#define NN 128
#define INF_ 5
#define LATD 3
#define HIDD 64

__device__ __forceinline__ float bflo(unsigned u) { return __uint_as_float(u << 16); }
__device__ __forceinline__ float bfhi(unsigned u) { return __uint_as_float(u & 0xffff0000u); }
__device__ __forceinline__ unsigned bfpack(float a, float b) {
    unsigned ua = __float_as_uint(a), ub = __float_as_uint(b);
    unsigned ra = (ua + 0x7fffu + ((ua >> 16) & 1u)) >> 16;   // RNE
    unsigned rb = (ub + 0x7fffu + ((ub >> 16) & 1u)) >> 16;
    return ra | (rb << 16);
}

// ---------------------------------------------------------------------------
// Encoder (f64, expressions unchanged across rounds -> adjacency bits stable).
// Also zeroes o5/o6. Grid (B,4).
// ---------------------------------------------------------------------------
__global__ __launch_bounds__(256) void enc_kernel(
    const float* __restrict__ batch,
    const float* __restrict__ w1, const float* __restrict__ b1,
    const float* __restrict__ w2, const float* __restrict__ b2,
    const float* __restrict__ w3, const float* __restrict__ b3,
    double* __restrict__ aos,
    float* __restrict__ o0, float* __restrict__ o1, float* __restrict__ o4,
    float* __restrict__ o5)
{
    const int b = blockIdx.x;
    const int n0 = blockIdx.y * 32;
    const int tid = threadIdx.x;
    const int w = tid >> 6, lane = tid & 63;

    {   // zero adj + edge_dist (contiguous 8 MB starting at o5)
        const int blk = blockIdx.x * 4 + blockIdx.y;      // 0..255
        float4* z = (float4*)o5 + (size_t)blk * 2048;
        float4 zero = make_float4(0.f, 0.f, 0.f, 0.f);
        for (int q = tid; q < 2048; q += 256) z[q] = zero;
    }

    __shared__ double xs[32][6];
    __shared__ double w1s[INF_][HIDD];
    __shared__ float  w2s[HIDD * HIDD];
    __shared__ double w3s[HIDD][LATD];
    __shared__ double b1s[HIDD], b2s[HIDD], b3s[LATD];

    for (int idx = tid; idx < 32 * INF_; idx += 256) {
        int n = idx / INF_, c = idx % INF_;
        float v = batch[((size_t)b * NN + n0 + n) * INF_ + c];
        xs[n][c] = (double)v;
        if (c < 4) o0[((size_t)b * NN + n0 + n) * 4 + c] = v;
        else       o1[(size_t)b * NN + n0 + n] = v;
    }
    for (int idx = tid; idx < INF_ * HIDD; idx += 256)
        w1s[idx / HIDD][idx % HIDD] = (double)w1[idx];
    for (int idx = tid; idx < HIDD * HIDD; idx += 256)
        w2s[idx] = w2[idx];
    for (int idx = tid; idx < HIDD * LATD; idx += 256)
        w3s[idx / LATD][idx % LATD] = (double)w3[idx];
    if (tid < HIDD) {
        b1s[tid] = (double)b1[tid];
        b2s[tid] = (double)b2[tid];
    }
    if (tid < LATD) b3s[tid] = (double)b3[tid];
    __syncthreads();

    for (int r = 0; r < 8; ++r) {
        const int nl = w * 8 + r;
        const int n = n0 + nl;
        double h1v = b1s[lane];
        for (int k = 0; k < INF_; ++k) h1v += xs[nl][k] * w1s[k][lane];
        h1v = fmax(h1v, 0.0);
        double h2v = b2s[lane];
        for (int k = 0; k < HIDD; ++k) {
            double h1k = __shfl(h1v, k, 64);
            h2v += h1k * (double)w2s[k * HIDD + lane];
        }
        h2v = fmax(h2v, 0.0);
        double l0 = h2v * w3s[lane][0];
        double l1 = h2v * w3s[lane][1];
        double l2 = h2v * w3s[lane][2];
        for (int o = 32; o >= 1; o >>= 1) {
            l0 += __shfl_xor(l0, o, 64);
            l1 += __shfl_xor(l1, o, 64);
            l2 += __shfl_xor(l2, o, 64);
        }
        l0 += b3s[0]; l1 += b3s[1]; l2 += b3s[2];
        if (lane == 0) {
            double* A = aos + ((size_t)b * NN + n) * 4;
            A[0] = l0; A[1] = l1; A[2] = l2;
            A[3] = l0 * l0 + l1 * l1 + l2 * l2;
        }
        if (lane < LATD) {
            double lv = (lane == 0) ? l0 : ((lane == 1) ? l1 : l2);
            o4[((size_t)b * NN + n) * LATD + lane] = (float)lv;
        }
    }
}

// ---------------------------------------------------------------------------
// Gabriel v5 (unchanged from r9): wave = pair stream with j-parity split,
// lane = witness k in registers, identity d2-r2 == (pk-pi).(pk-pj).
// ---------------------------------------------------------------------------
__global__ __launch_bounds__(256) void gabriel_kernel(
    const double* __restrict__ aos,
    float* __restrict__ o5, float* __restrict__ o6)
{
    const int b = blockIdx.y;
    const int w = threadIdx.x >> 6, lane = threadIdx.x & 63;
    const int u = blockIdx.x * 4 + w;          // 0..127
    const int v = u >> 1, par = u & 1;

    __shared__ double4 Ps[NN];
    const double2* src = (const double2*)(aos + (size_t)b * NN * 4);
    double2* dst = (double2*)Ps;
    for (int idx = threadIdx.x; idx < NN * 2; idx += 256) dst[idx] = src[idx];
    __syncthreads();

    const double4 A  = Ps[lane];
    const double4 Bq = Ps[lane + 64];

    for (int half = 0; half < 2; ++half) {
        const int i = (half == 0) ? v : 126 - v;
        if (half == 1 && i == v) break;
        const int jstart = (half == 0) ? (v + 1) : (127 - v);
        const int j0 = jstart + ((jstart ^ par) & 1);
        const double4 pi = Ps[i];
        const double aix = A.x - pi.x,  aiy = A.y - pi.y,  aiz = A.z - pi.z;
        const double bix = Bq.x - pi.x, biy = Bq.y - pi.y, biz = Bq.z - pi.z;
        const bool mA = (lane != i), mB = (lane + 64 != i);
        for (int j = j0; j < NN; j += 2) {
            double4 pj = Ps[j];
            double ajx = A.x - pj.x,  ajy = A.y - pj.y,  ajz = A.z - pj.z;
            double bjx = Bq.x - pj.x, bjy = Bq.y - pj.y, bjz = Bq.z - pj.z;
            double dA = aix * ajx + aiy * ajy + aiz * ajz;
            double dB = bix * bjx + biy * bjy + biz * bjz;
            bool tA = (dA < 0.0) && mA && (lane != j);
            bool tB = (dB < 0.0) && mB && (lane + 64 != j);
            if (!__any(tA || tB)) {
                if (lane == 0) {
                    double dx = pi.x - pj.x, dy = pi.y - pj.y, dz = pi.z - pj.z;
                    float d = (float)sqrt(dx * dx + dy * dy + dz * dz);
                    size_t ij = ((size_t)b * NN + i) * NN + j;
                    size_t ji = ((size_t)b * NN + j) * NN + i;
                    o5[ij] = 1.0f; o5[ji] = 1.0f;
                    o6[ij] = d;    o6[ji] = d;
                }
            }
        }
    }
}

// ---------------------------------------------------------------------------
// Linear stage -> packed bf16x2 hl/hr scratch (unchanged from r9).
// ---------------------------------------------------------------------------
template <int CIN>
__device__ __forceinline__ void lin_body(
    int b, int n0, const float* __restrict__ xin, const float* __restrict__ latf,
    const float* __restrict__ wl, const float* __restrict__ bl,
    const float* __restrict__ wr, const float* __restrict__ br,
    unsigned* __restrict__ hlp, unsigned* __restrict__ hrp,
    float4* xs4, int tid)
{
    float* xsh = (float*)xs4;
    if constexpr (CIN == 64) {
        const float4* src = (const float4*)(xin + ((size_t)b * NN + n0) * HIDD);
        for (int idx = tid; idx < 32 * 16; idx += 256) xs4[idx] = src[idx];
    } else {
        if (tid < 32) xsh[tid] = latf[((size_t)b * NN + n0 + tid) * LATD + 2];
    }
    __syncthreads();

    const int w = tid >> 6, lane = tid & 63;
    float wc[CIN];
    #pragma unroll
    for (int k = 0; k < CIN; ++k) wc[k] = wl[k * HIDD + lane];
    float bv = bl[lane];
    for (int m = 0; m < 8; ++m) {
        int nl = w * 8 + m;
        float acc = bv;
        if constexpr (CIN == 64) {
            #pragma unroll
            for (int t = 0; t < 16; ++t) {
                float4 q = xs4[nl * 16 + t];
                acc = fmaf(q.x, wc[4 * t + 0], acc);
                acc = fmaf(q.y, wc[4 * t + 1], acc);
                acc = fmaf(q.z, wc[4 * t + 2], acc);
                acc = fmaf(q.w, wc[4 * t + 3], acc);
            }
        } else acc = fmaf(xsh[nl], wc[0], acc);
        float partner = __shfl_xor(acc, 1, 64);
        if ((lane & 1) == 0)
            hlp[((size_t)b * NN + n0 + nl) * 32 + (lane >> 1)] = bfpack(acc, partner);
    }
    #pragma unroll
    for (int k = 0; k < CIN; ++k) wc[k] = wr[k * HIDD + lane];
    bv = br[lane];
    for (int m = 0; m < 8; ++m) {
        int nl = w * 8 + m;
        float acc = bv;
        if constexpr (CIN == 64) {
            #pragma unroll
            for (int t = 0; t < 16; ++t) {
                float4 q = xs4[nl * 16 + t];
                acc = fmaf(q.x, wc[4 * t + 0], acc);
                acc = fmaf(q.y, wc[4 * t + 1], acc);
                acc = fmaf(q.z, wc[4 * t + 2], acc);
                acc = fmaf(q.w, wc[4 * t + 3], acc);
            }
        } else acc = fmaf(xsh[nl], wc[0], acc);
        float partner = __shfl_xor(acc, 1, 64);
        if ((lane & 1) == 0)
            hrp[((size_t)b * NN + n0 + nl) * 32 + (lane >> 1)] = bfpack(acc, partner);
    }
}

template <int CIN>
__global__ __launch_bounds__(256) void lin_kernel(
    const float* __restrict__ xin, const float* __restrict__ latf,
    const float* __restrict__ wl, const float* __restrict__ bl,
    const float* __restrict__ wr, const float* __restrict__ br,
    unsigned* __restrict__ hlp, unsigned* __restrict__ hrp)
{
    __shared__ float4 xs4[(CIN == 64) ? 32 * 16 : 8];
    lin_body<CIN>(blockIdx.x >> 2, (blockIdx.x & 3) << 5, xin, latf,
                  wl, bl, wr, br, hlp, hrp, xs4, threadIdx.x);
}

__global__ __launch_bounds__(256) void lin34_kernel(
    const float* __restrict__ xin,
    const float* __restrict__ wl3, const float* __restrict__ bl3,
    const float* __restrict__ wr3, const float* __restrict__ br3,
    const float* __restrict__ wl4, const float* __restrict__ bl4,
    const float* __restrict__ wr4, const float* __restrict__ br4,
    unsigned* __restrict__ hl3p, unsigned* __restrict__ hr3p,
    unsigned* __restrict__ hl4p, unsigned* __restrict__ hr4p)
{
    __shared__ float4 xs4[32 * 16];
    const int b = blockIdx.x >> 2, n0 = (blockIdx.x & 3) << 5;
    if (blockIdx.y == 0)
        lin_body<64>(b, n0, xin, nullptr, wl3, bl3, wr3, br3, hl3p, hr3p, xs4, threadIdx.x);
    else
        lin_body<64>(b, n0, xin, nullptr, wl4, bl4, wr4, br4, hl4p, hr4p, xs4, threadIdx.x);
}

// ---------------------------------------------------------------------------
// Attention v3 — occupancy-first (r9 lesson: readlane + 128-reg hoist killed
// occupancy at 18.6% and added VALU). 8 rows/block -> 1024 blocks/layer;
// LDS = 40,192 B exactly (4 blocks/CU, 16 waves/CU); no register hoist, no
// readlane; uniform data via float2 LDS broadcasts. 2 rows/wave share every
// hl read. lrelu = fmaxf(e, 0.2e).
// ---------------------------------------------------------------------------
struct AttnS {
    float  hls[NN * 66];     // 33792 B; PhaseA own-reads float2 (4-way ok),
    float2 as2[4][NN];       //  4096 B; per-wave a-values      PhaseB b32 2-way
    float2 hr2[8][32];       //  2048 B; hr rows as f32 pairs (broadcast)
    float2 att2[32];         //   256 B; att as f32 pairs (broadcast)
};

template <int C>
__device__ __forceinline__ void attn_v3(
    int b, int i0, int tid, AttnS& s,
    const unsigned* __restrict__ hlp, const unsigned* __restrict__ hrp,
    const float* __restrict__ att, const float* __restrict__ bias,
    const float* __restrict__ adjf, const float* __restrict__ latf,
    const float* __restrict__ skw, const float* __restrict__ skb,
    float* __restrict__ xout,
    const float* __restrict__ head_w, const float* __restrict__ head_b,
    float* __restrict__ head_out)
{
    const int w = tid >> 6, lane = tid & 63;

    // ---- stage ----
    {
        const unsigned* src = hlp + (size_t)b * NN * 32;
        for (int idx = tid; idx < NN * 32; idx += 256) {
            int j = idx >> 5, c = idx & 31;
            unsigned u = src[idx];
            *(float2*)&s.hls[j * 66 + 2 * c] = make_float2(bflo(u), bfhi(u));
        }
        unsigned u = hrp[((size_t)b * NN + i0) * 32 + tid];   // 256 = 8 rows * 32
        ((float2*)s.hr2)[tid] = make_float2(bflo(u), bfhi(u));
        if (tid < 32) s.att2[tid] = make_float2(att[2 * tid], att[2 * tid + 1]);
    }
    // per-lane params (registers; no LDS)
    float bsv = bias[lane];
    float sw0 = 0.f, sw1 = 0.f, sw2 = 0.f, sbv = 0.f;
    if (skw != nullptr) {
        sw0 = skw[lane]; sw1 = skw[64 + lane]; sw2 = skw[128 + lane];
        sbv = skb[lane];
    }
    __syncthreads();

    const int il0 = w * 2, il1 = il0 + 1;
    const int i_0 = i0 + il0, i_1 = i0 + il1;

    // ---- Phase A: scores for 2 rows x 2 column-halves ----
    float s00 = 0.f, s01 = 0.f, s10 = 0.f, s11 = 0.f;
    {
        const float* hl0 = &s.hls[lane * 66];
        const float* hl1 = &s.hls[(lane + 64) * 66];
        #pragma unroll
        for (int c = 0; c < 32; ++c) {
            float2 av = s.att2[c];
            float2 r0 = s.hr2[il0][c];
            float2 r1 = s.hr2[il1][c];
            float2 g0 = *(const float2*)&hl0[2 * c];
            float2 g1 = *(const float2*)&hl1[2 * c];
            float e;
            e = r0.x + g0.x; e = fmaxf(e, 0.2f * e); s00 = fmaf(av.x, e, s00);
            e = r0.y + g0.y; e = fmaxf(e, 0.2f * e); s00 = fmaf(av.y, e, s00);
            e = r0.x + g1.x; e = fmaxf(e, 0.2f * e); s01 = fmaf(av.x, e, s01);
            e = r0.y + g1.y; e = fmaxf(e, 0.2f * e); s01 = fmaf(av.y, e, s01);
            e = r1.x + g0.x; e = fmaxf(e, 0.2f * e); s10 = fmaf(av.x, e, s10);
            e = r1.y + g0.y; e = fmaxf(e, 0.2f * e); s10 = fmaf(av.y, e, s10);
            e = r1.x + g1.x; e = fmaxf(e, 0.2f * e); s11 = fmaf(av.x, e, s11);
            e = r1.y + g1.y; e = fmaxf(e, 0.2f * e); s11 = fmaf(av.y, e, s11);
        }
    }
    // adjacency masks (coalesced global; self-loops added here)
    {
        const float* ar0 = adjf + ((size_t)b * NN + i_0) * NN;
        const float* ar1 = adjf + ((size_t)b * NN + i_1) * NN;
        if (!((ar0[lane] != 0.f)      || (lane == i_0)))      s00 = -1e30f;
        if (!((ar0[lane + 64] != 0.f) || (lane + 64 == i_0))) s01 = -1e30f;
        if (!((ar1[lane] != 0.f)      || (lane == i_1)))      s10 = -1e30f;
        if (!((ar1[lane + 64] != 0.f) || (lane + 64 == i_1))) s11 = -1e30f;
    }
    // ---- 2 softmaxes over 128 columns ----
    float m0 = fmaxf(s00, s01), m1 = fmaxf(s10, s11);
    for (int o = 32; o >= 1; o >>= 1) {
        m0 = fmaxf(m0, __shfl_xor(m0, o, 64));
        m1 = fmaxf(m1, __shfl_xor(m1, o, 64));
    }
    float e00 = __expf(s00 - m0), e01 = __expf(s01 - m0);
    float e10 = __expf(s10 - m1), e11 = __expf(s11 - m1);
    float z0 = e00 + e01, z1 = e10 + e11;
    for (int o = 32; o >= 1; o >>= 1) {
        z0 += __shfl_xor(z0, o, 64);
        z1 += __shfl_xor(z1, o, 64);
    }
    float iv0 = 1.f / z0, iv1 = 1.f / z1;
    s.as2[w][lane]      = make_float2(e00 * iv0, e10 * iv1);
    s.as2[w][lane + 64] = make_float2(e01 * iv0, e11 * iv1);
    // wave-private LDS row; same-wave LDS ordering is guaranteed (lgkmcnt)

    // ---- Phase B: joint aggregation, lane = h ----
    float o0a = 0.f, o1a = 0.f;
    for (int j = 0; j < NN; ++j) {
        float2 av = s.as2[w][j];            // broadcast b64
        float hv = s.hls[j * 66 + lane];    // 2-way alias, free
        o0a = fmaf(av.x, hv, o0a);
        o1a = fmaf(av.y, hv, o1a);
    }

    // ---- epilogue for 2 rows ----
    #pragma unroll
    for (int r = 0; r < 2; ++r) {
        const int i = (r == 0) ? i_0 : i_1;
        float out = ((r == 0) ? o0a : o1a) + bsv;
        if (skw != nullptr) {
            const float* lr = latf + ((size_t)b * NN + i) * LATD;
            float sk = sbv;
            sk = fmaf(lr[0], sw0, sk);
            sk = fmaf(lr[1], sw1, sk);
            sk = fmaf(lr[2], sw2, sk);
            out += 0.1f * sk;
        }
        out = fmaxf(out, 0.f);
        if constexpr (C == 0) {
            xout[((size_t)b * NN + i) * HIDD + lane] = out;
        } else {
            float hv[C > 0 ? C : 1];
            #pragma unroll
            for (int c = 0; c < C; ++c) {
                float vv = out * head_w[lane * C + c];
                for (int o = 32; o >= 1; o >>= 1) vv += __shfl_xor(vv, o, 64);
                hv[c] = vv + head_b[c];
            }
            if (lane == 0)
                for (int c = 0; c < C; ++c)
                    head_out[((size_t)b * NN + i) * C + c] = hv[c];
        }
    }
}

__global__ __launch_bounds__(256, 4) void attn12_kernel(
    const unsigned* __restrict__ hlp, const unsigned* __restrict__ hrp,
    const float* __restrict__ att, const float* __restrict__ bias,
    const float* __restrict__ adjf, float* __restrict__ xout)
{
    __shared__ AttnS s;
    attn_v3<0>(blockIdx.x >> 4, (blockIdx.x & 15) << 3, threadIdx.x, s,
               hlp, hrp, att, bias, adjf, nullptr, nullptr, nullptr,
               xout, nullptr, nullptr, nullptr);
}

__global__ __launch_bounds__(256, 4) void attn34_kernel(
    const unsigned* __restrict__ hl3p, const unsigned* __restrict__ hr3p,
    const unsigned* __restrict__ hl4p, const unsigned* __restrict__ hr4p,
    const float* __restrict__ att3, const float* __restrict__ b3,
    const float* __restrict__ att4, const float* __restrict__ b4,
    const float* __restrict__ adjf, const float* __restrict__ latf,
    const float* __restrict__ skw, const float* __restrict__ skb,
    const float* __restrict__ lab_w, const float* __restrict__ lab_b, float* __restrict__ o2,
    const float* __restrict__ val_w, const float* __restrict__ val_b, float* __restrict__ o3)
{
    __shared__ AttnS s;
    const int b = blockIdx.x >> 4, i0 = (blockIdx.x & 15) << 3;
    if (blockIdx.y == 0)
        attn_v3<4>(b, i0, threadIdx.x, s, hl3p, hr3p, att3, b3, adjf, latf,
                   skw, skb, nullptr, lab_w, lab_b, o2);
    else
        attn_v3<1>(b, i0, threadIdx.x, s, hl4p, hr4p, att4, b4, adjf, latf,
                   skw, skb, nullptr, val_w, val_b, o3);
}

// ---------------------------------------------------------------------------
extern "C" void kernel_launch(void* const* d_in, const int* in_sizes, int n_in,
                              void* d_out, int out_size, void* d_ws, size_t ws_size,
                              hipStream_t stream)
{
    const float* batch  = (const float*)d_in[0];
    const float* enc_w1 = (const float*)d_in[1];
    const float* enc_b1 = (const float*)d_in[2];
    const float* enc_w2 = (const float*)d_in[3];
    const float* enc_b2 = (const float*)d_in[4];
    const float* enc_w3 = (const float*)d_in[5];
    const float* enc_b3 = (const float*)d_in[6];
    const float* g_wl[4]  = {(const float*)d_in[7],  (const float*)d_in[13], (const float*)d_in[19], (const float*)d_in[25]};
    const float* g_bl[4]  = {(const float*)d_in[8],  (const float*)d_in[14], (const float*)d_in[20], (const float*)d_in[26]};
    const float* g_wr[4]  = {(const float*)d_in[9],  (const float*)d_in[15], (const float*)d_in[21], (const float*)d_in[27]};
    const float* g_br[4]  = {(const float*)d_in[10], (const float*)d_in[16], (const float*)d_in[22], (const float*)d_in[28]};
    const float* g_att[4] = {(const float*)d_in[11], (const float*)d_in[17], (const float*)d_in[23], (const float*)d_in[29]};
    const float* g_b[4]   = {(const float*)d_in[12], (const float*)d_in[18], (const float*)d_in[24], (const float*)d_in[30]};
    const float* lab_w = (const float*)d_in[31];
    const float* lab_b = (const float*)d_in[32];
    const float* val_w = (const float*)d_in[33];
    const float* val_b = (const float*)d_in[34];
    const float* skw   = (const float*)d_in[35];
    const float* skb   = (const float*)d_in[36];

    float* out = (float*)d_out;
    float* o0 = out;            // batch[:,:,:4]   32768
    float* o1 = out + 32768;    // batch[:,:,4:5]   8192
    float* o2 = out + 40960;    // logits          32768
    float* o3 = out + 73728;    // values           8192
    float* o4 = out + 81920;    // latent          24576  (doubles as latf)
    float* o5 = out + 106496;   // adj           1048576
    float* o6 = out + 1155072;  // edge_dist     1048576

    char* p = (char*)d_ws;
    auto carve = [&](size_t bytes) { void* r = (void*)p; p += (bytes + 255) & ~(size_t)255; return r; };
    double*   aos  = (double*)  carve((size_t)BB * NN * 4 * 8);      // 256 KB
    float*    xA   = (float*)   carve((size_t)BB * NN * HIDD * 4);   // 2 MB
    float*    xB   = (float*)   carve((size_t)BB * NN * HIDD * 4);   // 2 MB
    unsigned* hlp  = (unsigned*)carve((size_t)BB * NN * 32 * 4);     // 1 MB
    unsigned* hrp  = (unsigned*)carve((size_t)BB * NN * 32 * 4);     // 1 MB
    unsigned* hl3p = (unsigned*)carve((size_t)BB * NN * 32 * 4);     // 1 MB
    unsigned* hr3p = (unsigned*)carve((size_t)BB * NN * 32 * 4);     // 1 MB

    enc_kernel<<<dim3(BB, 4), 256, 0, stream>>>(batch, enc_w1, enc_b1, enc_w2, enc_b2,
                                                enc_w3, enc_b3, aos, o0, o1, o4, o5);
    gabriel_kernel<<<dim3(32, BB), 256, 0, stream>>>(aos, o5, o6);

    // layer 1 (Cin=1, x0 = latent[...,2]) -> xA
    lin_kernel<1><<<BB * 4, 256, 0, stream>>>(nullptr, o4, g_wl[0], g_bl[0], g_wr[0], g_br[0], hlp, hrp);
    attn12_kernel<<<BB * 16, 256, 0, stream>>>(hlp, hrp, g_att[0], g_b[0], o5, xA);
    // layer 2 -> xB
    lin_kernel<64><<<BB * 4, 256, 0, stream>>>(xA, nullptr, g_wl[1], g_bl[1], g_wr[1], g_br[1], hlp, hrp);
    attn12_kernel<<<BB * 16, 256, 0, stream>>>(hlp, hrp, g_att[1], g_b[1], o5, xB);
    // layers 3+4 fused (both read xB)
    lin34_kernel<<<dim3(BB * 4, 2), 256, 0, stream>>>(xB,
        g_wl[2], g_bl[2], g_wr[2], g_br[2], g_wl[3], g_bl[3], g_wr[3], g_br[3],
        hl3p, hr3p, hlp, hrp);
    attn34_kernel<<<dim3(BB * 16, 2), 256, 0, stream>>>(hl3p, hr3p, hlp, hrp,
        g_att[2], g_b[2], g_att[3], g_b[3], o5, o4, skw, skb,
        lab_w, lab_b, o2, val_w, val_b, o3);
}

// Round 11
// 298.341 us; speedup vs baseline: 1.1161x; 1.0219x over previous
//
#include <hip/hip_runtime.h>

#define BB 64
#define NN 128
#define INF_ 5
#define LATD 3
#define HIDD 64

__device__ __forceinline__ float bflo(unsigned u) { return __uint_as_float(u << 16); }
__device__ __forceinline__ float bfhi(unsigned u) { return __uint_as_float(u & 0xffff0000u); }
__device__ __forceinline__ unsigned bfpack(float a, float b) {
    unsigned ua = __float_as_uint(a), ub = __float_as_uint(b);
    unsigned ra = (ua + 0x7fffu + ((ua >> 16) & 1u)) >> 16;   // RNE
    unsigned rb = (ub + 0x7fffu + ((ub >> 16) & 1u)) >> 16;
    return ra | (rb << 16);
}

// ---------------------------------------------------------------------------
// Encoder (f64, expressions unchanged since r5 -> adjacency bits stable).
// Also zeroes o5/o6. Grid (B,4).
// ---------------------------------------------------------------------------
__global__ __launch_bounds__(256) void enc_kernel(
    const float* __restrict__ batch,
    const float* __restrict__ w1, const float* __restrict__ b1,
    const float* __restrict__ w2, const float* __restrict__ b2,
    const float* __restrict__ w3, const float* __restrict__ b3,
    double* __restrict__ aos,
    float* __restrict__ o0, float* __restrict__ o1, float* __restrict__ o4,
    float* __restrict__ o5)
{
    const int b = blockIdx.x;
    const int n0 = blockIdx.y * 32;
    const int tid = threadIdx.x;
    const int w = tid >> 6, lane = tid & 63;

    {   // zero adj + edge_dist (contiguous 8 MB starting at o5)
        const int blk = blockIdx.x * 4 + blockIdx.y;      // 0..255
        float4* z = (float4*)o5 + (size_t)blk * 2048;
        float4 zero = make_float4(0.f, 0.f, 0.f, 0.f);
        for (int q = tid; q < 2048; q += 256) z[q] = zero;
    }

    __shared__ double xs[32][6];
    __shared__ double w1s[INF_][HIDD];
    __shared__ float  w2s[HIDD * HIDD];
    __shared__ double w3s[HIDD][LATD];
    __shared__ double b1s[HIDD], b2s[HIDD], b3s[LATD];

    for (int idx = tid; idx < 32 * INF_; idx += 256) {
        int n = idx / INF_, c = idx % INF_;
        float v = batch[((size_t)b * NN + n0 + n) * INF_ + c];
        xs[n][c] = (double)v;
        if (c < 4) o0[((size_t)b * NN + n0 + n) * 4 + c] = v;
        else       o1[(size_t)b * NN + n0 + n] = v;
    }
    for (int idx = tid; idx < INF_ * HIDD; idx += 256)
        w1s[idx / HIDD][idx % HIDD] = (double)w1[idx];
    for (int idx = tid; idx < HIDD * HIDD; idx += 256)
        w2s[idx] = w2[idx];
    for (int idx = tid; idx < HIDD * LATD; idx += 256)
        w3s[idx / LATD][idx % LATD] = (double)w3[idx];
    if (tid < HIDD) {
        b1s[tid] = (double)b1[tid];
        b2s[tid] = (double)b2[tid];
    }
    if (tid < LATD) b3s[tid] = (double)b3[tid];
    __syncthreads();

    for (int r = 0; r < 8; ++r) {
        const int nl = w * 8 + r;
        const int n = n0 + nl;
        double h1v = b1s[lane];
        for (int k = 0; k < INF_; ++k) h1v += xs[nl][k] * w1s[k][lane];
        h1v = fmax(h1v, 0.0);
        double h2v = b2s[lane];
        for (int k = 0; k < HIDD; ++k) {
            double h1k = __shfl(h1v, k, 64);
            h2v += h1k * (double)w2s[k * HIDD + lane];
        }
        h2v = fmax(h2v, 0.0);
        double l0 = h2v * w3s[lane][0];
        double l1 = h2v * w3s[lane][1];
        double l2 = h2v * w3s[lane][2];
        for (int o = 32; o >= 1; o >>= 1) {
            l0 += __shfl_xor(l0, o, 64);
            l1 += __shfl_xor(l1, o, 64);
            l2 += __shfl_xor(l2, o, 64);
        }
        l0 += b3s[0]; l1 += b3s[1]; l2 += b3s[2];
        if (lane == 0) {
            double* A = aos + ((size_t)b * NN + n) * 4;
            A[0] = l0; A[1] = l1; A[2] = l2;
            A[3] = l0 * l0 + l1 * l1 + l2 * l2;
        }
        if (lane < LATD) {
            double lv = (lane == 0) ? l0 : ((lane == 1) ? l1 : l2);
            o4[((size_t)b * NN + n) * LATD + lane] = (float)lv;
        }
    }
}

// ---------------------------------------------------------------------------
// Gabriel (unchanged from r10): wave = pair stream with j-parity split,
// lane = witness k in registers, identity d2-r2 == (pk-pi).(pk-pj).
// ---------------------------------------------------------------------------
__global__ __launch_bounds__(256) void gabriel_kernel(
    const double* __restrict__ aos,
    float* __restrict__ o5, float* __restrict__ o6)
{
    const int b = blockIdx.y;
    const int w = threadIdx.x >> 6, lane = threadIdx.x & 63;
    const int u = blockIdx.x * 4 + w;          // 0..127
    const int v = u >> 1, par = u & 1;

    __shared__ double4 Ps[NN];
    const double2* src = (const double2*)(aos + (size_t)b * NN * 4);
    double2* dst = (double2*)Ps;
    for (int idx = threadIdx.x; idx < NN * 2; idx += 256) dst[idx] = src[idx];
    __syncthreads();

    const double4 A  = Ps[lane];
    const double4 Bq = Ps[lane + 64];

    for (int half = 0; half < 2; ++half) {
        const int i = (half == 0) ? v : 126 - v;
        if (half == 1 && i == v) break;
        const int jstart = (half == 0) ? (v + 1) : (127 - v);
        const int j0 = jstart + ((jstart ^ par) & 1);
        const double4 pi = Ps[i];
        const double aix = A.x - pi.x,  aiy = A.y - pi.y,  aiz = A.z - pi.z;
        const double bix = Bq.x - pi.x, biy = Bq.y - pi.y, biz = Bq.z - pi.z;
        const bool mA = (lane != i), mB = (lane + 64 != i);
        for (int j = j0; j < NN; j += 2) {
            double4 pj = Ps[j];
            double ajx = A.x - pj.x,  ajy = A.y - pj.y,  ajz = A.z - pj.z;
            double bjx = Bq.x - pj.x, bjy = Bq.y - pj.y, bjz = Bq.z - pj.z;
            double dA = aix * ajx + aiy * ajy + aiz * ajz;
            double dB = bix * bjx + biy * bjy + biz * bjz;
            bool tA = (dA < 0.0) && mA && (lane != j);
            bool tB = (dB < 0.0) && mB && (lane + 64 != j);
            if (!__any(tA || tB)) {
                if (lane == 0) {
                    double dx = pi.x - pj.x, dy = pi.y - pj.y, dz = pi.z - pj.z;
                    float d = (float)sqrt(dx * dx + dy * dy + dz * dz);
                    size_t ij = ((size_t)b * NN + i) * NN + j;
                    size_t ji = ((size_t)b * NN + j) * NN + i;
                    o5[ij] = 1.0f; o5[ji] = 1.0f;
                    o6[ij] = d;    o6[ji] = d;
                }
            }
        }
    }
}

// ---------------------------------------------------------------------------
// Attention building blocks (v4). 8 rows/block, 1024 blocks/layer, LDS =
// 40,192 B -> 4 blocks/CU (r10's occupancy-first structure, kept). NEW in
// v4: the next layer's linear is fused into the epilogue — the wave's 2
// output rows (lane = h) are matvec'd against W via __shfl broadcasts, with
// W staged into the then-dead hls LDS region. This deletes all lin kernels
// (r10: lin VGPR=256 + first-touch pathology = 87 us dispatch) and the
// xA/xB global round-trip.
// ---------------------------------------------------------------------------
struct AttnS {
    float  hls[NN * 66];     // 33792 B
    float2 as2[4][NN];       //  4096 B (wave-private)
    float2 hr2[8][32];       //  2048 B
    float2 att2[32];         //   256 B
};

__device__ __forceinline__ void attn_stage_packed(
    AttnS& s, int tid, int b, int i0,
    const unsigned* __restrict__ hlp, const unsigned* __restrict__ hrp,
    const float* __restrict__ att)
{
    const unsigned* src = hlp + (size_t)b * NN * 32;
    for (int idx = tid; idx < NN * 32; idx += 256) {
        int j = idx >> 5, c = idx & 31;
        unsigned u = src[idx];
        *(float2*)&s.hls[j * 66 + 2 * c] = make_float2(bflo(u), bfhi(u));
    }
    unsigned u = hrp[((size_t)b * NN + i0) * 32 + tid];   // 8 rows * 32 words
    ((float2*)s.hr2)[tid] = make_float2(bflo(u), bfhi(u));
    if (tid < 32) s.att2[tid] = make_float2(att[2 * tid], att[2 * tid + 1]);
}

// Phase A (scores+softmax) + Phase B (aggregation). Caller barriers staging.
__device__ __forceinline__ void attn_phase(
    AttnS& s, int b, int i0, int w, int lane,
    const float* __restrict__ adjf, float& agg0, float& agg1)
{
    const int il0 = w * 2, il1 = il0 + 1;
    const int i_0 = i0 + il0, i_1 = i0 + il1;
    float s00 = 0.f, s01 = 0.f, s10 = 0.f, s11 = 0.f;
    {
        const float* hl0 = &s.hls[lane * 66];
        const float* hl1 = &s.hls[(lane + 64) * 66];
        #pragma unroll
        for (int c = 0; c < 32; ++c) {
            float2 av = s.att2[c];
            float2 r0 = s.hr2[il0][c];
            float2 r1 = s.hr2[il1][c];
            float2 g0 = *(const float2*)&hl0[2 * c];
            float2 g1 = *(const float2*)&hl1[2 * c];
            float e;
            e = r0.x + g0.x; e = fmaxf(e, 0.2f * e); s00 = fmaf(av.x, e, s00);
            e = r0.y + g0.y; e = fmaxf(e, 0.2f * e); s00 = fmaf(av.y, e, s00);
            e = r0.x + g1.x; e = fmaxf(e, 0.2f * e); s01 = fmaf(av.x, e, s01);
            e = r0.y + g1.y; e = fmaxf(e, 0.2f * e); s01 = fmaf(av.y, e, s01);
            e = r1.x + g0.x; e = fmaxf(e, 0.2f * e); s10 = fmaf(av.x, e, s10);
            e = r1.y + g0.y; e = fmaxf(e, 0.2f * e); s10 = fmaf(av.y, e, s10);
            e = r1.x + g1.x; e = fmaxf(e, 0.2f * e); s11 = fmaf(av.x, e, s11);
            e = r1.y + g1.y; e = fmaxf(e, 0.2f * e); s11 = fmaf(av.y, e, s11);
        }
    }
    {
        const float* ar0 = adjf + ((size_t)b * NN + i_0) * NN;
        const float* ar1 = adjf + ((size_t)b * NN + i_1) * NN;
        if (!((ar0[lane] != 0.f)      || (lane == i_0)))      s00 = -1e30f;
        if (!((ar0[lane + 64] != 0.f) || (lane + 64 == i_0))) s01 = -1e30f;
        if (!((ar1[lane] != 0.f)      || (lane == i_1)))      s10 = -1e30f;
        if (!((ar1[lane + 64] != 0.f) || (lane + 64 == i_1))) s11 = -1e30f;
    }
    float m0 = fmaxf(s00, s01), m1 = fmaxf(s10, s11);
    for (int o = 32; o >= 1; o >>= 1) {
        m0 = fmaxf(m0, __shfl_xor(m0, o, 64));
        m1 = fmaxf(m1, __shfl_xor(m1, o, 64));
    }
    float e00 = __expf(s00 - m0), e01 = __expf(s01 - m0);
    float e10 = __expf(s10 - m1), e11 = __expf(s11 - m1);
    float z0 = e00 + e01, z1 = e10 + e11;
    for (int o = 32; o >= 1; o >>= 1) {
        z0 += __shfl_xor(z0, o, 64);
        z1 += __shfl_xor(z1, o, 64);
    }
    float iv0 = 1.f / z0, iv1 = 1.f / z1;
    s.as2[w][lane]      = make_float2(e00 * iv0, e10 * iv1);
    s.as2[w][lane + 64] = make_float2(e01 * iv0, e11 * iv1);
    float o0a = 0.f, o1a = 0.f;
    for (int j = 0; j < NN; ++j) {
        float2 av = s.as2[w][j];
        float hv = s.hls[j * 66 + lane];
        o0a = fmaf(av.x, hv, o0a);
        o1a = fmaf(av.y, hv, o1a);
    }
    agg0 = o0a; agg1 = o1a;
}

// Fused next-layer linear: out rows (lane=h) @ wmat -> packed bf16x2 global.
// Stages wmat into the dead hls region (barrier-guarded).
__device__ __forceinline__ void matvec_store(
    AttnS& s, int tid, int w, int lane, float out0, float out1,
    int b, int i0, const float* __restrict__ wmat, const float* __restrict__ bvec,
    unsigned* __restrict__ outp)
{
    __syncthreads();                                    // all waves done with hls
    for (int idx = tid; idx < HIDD * HIDD; idx += 256) s.hls[idx] = wmat[idx];
    __syncthreads();
    float acc0 = bvec[lane], acc1 = acc0;
    for (int h = 0; h < HIDD; ++h) {
        float wv = s.hls[h * HIDD + lane];              // bank=lane%32, free
        acc0 = fmaf(__shfl(out0, h, 64), wv, acc0);
        acc1 = fmaf(__shfl(out1, h, 64), wv, acc1);
    }
    float p0 = __shfl_xor(acc0, 1, 64);
    float p1 = __shfl_xor(acc1, 1, 64);
    if ((lane & 1) == 0) {
        outp[((size_t)b * NN + i0 + w * 2 + 0) * 32 + (lane >> 1)] = bfpack(acc0, p0);
        outp[((size_t)b * NN + i0 + w * 2 + 1) * 32 + (lane >> 1)] = bfpack(acc1, p1);
    }
}

// ---- layer 1: lin1 folded into staging (Cin=1), lin2 folded into epilogue --
__global__ __launch_bounds__(256, 4) void attnA_kernel(
    const float* __restrict__ latf,
    const float* __restrict__ wl1, const float* __restrict__ bl1,
    const float* __restrict__ wr1, const float* __restrict__ br1,
    const float* __restrict__ att, const float* __restrict__ bias,
    const float* __restrict__ adjf,
    const float* __restrict__ wl2, const float* __restrict__ bl2,
    const float* __restrict__ wr2, const float* __restrict__ br2,
    unsigned* __restrict__ hl2p, unsigned* __restrict__ hr2p)
{
    __shared__ AttnS s;
    const int bx = blockIdx.x;
    const int b = bx >> 4, i0 = (bx & 15) << 3;
    const int tid = threadIdx.x, w = tid >> 6, lane = tid & 63;

    {   // hl1[j][h] = x0[j]*wl1[h] + bl1[h];  x0 = latent[...,2] (wave-uniform)
        float wv = wl1[lane], bv = bl1[lane];
        for (int m = 0; m < 32; ++m) {
            int j = w + 4 * m;
            float x0 = latf[((size_t)b * NN + j) * LATD + 2];
            s.hls[j * 66 + lane] = fmaf(x0, wv, bv);
        }
    }
    {   // hr1 for this block's 8 rows
        int il = tid >> 5, c = tid & 31;
        float x0 = latf[((size_t)b * NN + i0 + il) * LATD + 2];
        s.hr2[il][c] = make_float2(fmaf(x0, wr1[2 * c], br1[2 * c]),
                                   fmaf(x0, wr1[2 * c + 1], br1[2 * c + 1]));
    }
    if (tid < 32) s.att2[tid] = make_float2(att[2 * tid], att[2 * tid + 1]);
    float bsv = bias[lane];
    __syncthreads();

    float agg0, agg1;
    attn_phase(s, b, i0, w, lane, adjf, agg0, agg1);
    float out0 = fmaxf(agg0 + bsv, 0.f);
    float out1 = fmaxf(agg1 + bsv, 0.f);

    matvec_store(s, tid, w, lane, out0, out1, b, i0, wl2, bl2, hl2p);
    matvec_store(s, tid, w, lane, out0, out1, b, i0, wr2, br2, hr2p);
}

// ---- layer 2: lin3 + lin4 folded into epilogue ----------------------------
__global__ __launch_bounds__(256, 4) void attnB_kernel(
    const unsigned* __restrict__ hlp, const unsigned* __restrict__ hrp,
    const float* __restrict__ att, const float* __restrict__ bias,
    const float* __restrict__ adjf,
    const float* __restrict__ wl3, const float* __restrict__ bl3,
    const float* __restrict__ wr3, const float* __restrict__ br3,
    const float* __restrict__ wl4, const float* __restrict__ bl4,
    const float* __restrict__ wr4, const float* __restrict__ br4,
    unsigned* __restrict__ hl3p, unsigned* __restrict__ hr3p,
    unsigned* __restrict__ hl4p, unsigned* __restrict__ hr4p)
{
    __shared__ AttnS s;
    const int bx = blockIdx.x;
    const int b = bx >> 4, i0 = (bx & 15) << 3;
    const int tid = threadIdx.x, w = tid >> 6, lane = tid & 63;

    attn_stage_packed(s, tid, b, i0, hlp, hrp, att);
    float bsv = bias[lane];
    __syncthreads();

    float agg0, agg1;
    attn_phase(s, b, i0, w, lane, adjf, agg0, agg1);
    float out0 = fmaxf(agg0 + bsv, 0.f);
    float out1 = fmaxf(agg1 + bsv, 0.f);

    matvec_store(s, tid, w, lane, out0, out1, b, i0, wl3, bl3, hl3p);
    matvec_store(s, tid, w, lane, out0, out1, b, i0, wr3, br3, hr3p);
    matvec_store(s, tid, w, lane, out0, out1, b, i0, wl4, bl4, hl4p);
    matvec_store(s, tid, w, lane, out0, out1, b, i0, wr4, br4, hr4p);
}

// ---- layers 3 & 4: skip + output heads ------------------------------------
template <int C>
__device__ __forceinline__ void attn_head(
    AttnS& s, int tid, int b, int i0,
    const unsigned* __restrict__ hlp, const unsigned* __restrict__ hrp,
    const float* __restrict__ att, const float* __restrict__ bias,
    const float* __restrict__ adjf, const float* __restrict__ latf,
    const float* __restrict__ skw, const float* __restrict__ skb,
    const float* __restrict__ head_w, const float* __restrict__ head_b,
    float* __restrict__ head_out)
{
    const int w = tid >> 6, lane = tid & 63;
    attn_stage_packed(s, tid, b, i0, hlp, hrp, att);
    float bsv = bias[lane];
    float sw0 = skw[lane], sw1 = skw[64 + lane], sw2 = skw[128 + lane];
    float sbv = skb[lane];
    __syncthreads();

    float agg0, agg1;
    attn_phase(s, b, i0, w, lane, adjf, agg0, agg1);

    #pragma unroll
    for (int r = 0; r < 2; ++r) {
        const int i = i0 + w * 2 + r;
        float out = ((r == 0) ? agg0 : agg1) + bsv;
        const float* lr = latf + ((size_t)b * NN + i) * LATD;
        float sk = sbv;
        sk = fmaf(lr[0], sw0, sk);
        sk = fmaf(lr[1], sw1, sk);
        sk = fmaf(lr[2], sw2, sk);
        out = fmaxf(out + 0.1f * sk, 0.f);
        float hv[C];
        #pragma unroll
        for (int c = 0; c < C; ++c) {
            float vv = out * head_w[lane * C + c];
            for (int o = 32; o >= 1; o >>= 1) vv += __shfl_xor(vv, o, 64);
            hv[c] = vv + head_b[c];
        }
        if (lane == 0)
            for (int c = 0; c < C; ++c)
                head_out[((size_t)b * NN + i) * C + c] = hv[c];
    }
}

__global__ __launch_bounds__(256, 4) void attnCD_kernel(
    const unsigned* __restrict__ hl3p, const unsigned* __restrict__ hr3p,
    const unsigned* __restrict__ hl4p, const unsigned* __restrict__ hr4p,
    const float* __restrict__ att3, const float* __restrict__ b3,
    const float* __restrict__ att4, const float* __restrict__ b4,
    const float* __restrict__ adjf, const float* __restrict__ latf,
    const float* __restrict__ skw, const float* __restrict__ skb,
    const float* __restrict__ lab_w, const float* __restrict__ lab_b, float* __restrict__ o2,
    const float* __restrict__ val_w, const float* __restrict__ val_b, float* __restrict__ o3)
{
    __shared__ AttnS s;
    const int b = blockIdx.x >> 4, i0 = (blockIdx.x & 15) << 3;
    if (blockIdx.y == 0)
        attn_head<4>(s, threadIdx.x, b, i0, hl3p, hr3p, att3, b3, adjf, latf,
                     skw, skb, lab_w, lab_b, o2);
    else
        attn_head<1>(s, threadIdx.x, b, i0, hl4p, hr4p, att4, b4, adjf, latf,
                     skw, skb, val_w, val_b, o3);
}

// ---------------------------------------------------------------------------
extern "C" void kernel_launch(void* const* d_in, const int* in_sizes, int n_in,
                              void* d_out, int out_size, void* d_ws, size_t ws_size,
                              hipStream_t stream)
{
    const float* batch  = (const float*)d_in[0];
    const float* enc_w1 = (const float*)d_in[1];
    const float* enc_b1 = (const float*)d_in[2];
    const float* enc_w2 = (const float*)d_in[3];
    const float* enc_b2 = (const float*)d_in[4];
    const float* enc_w3 = (const float*)d_in[5];
    const float* enc_b3 = (const float*)d_in[6];
    const float* g_wl[4]  = {(const float*)d_in[7],  (const float*)d_in[13], (const float*)d_in[19], (const float*)d_in[25]};
    const float* g_bl[4]  = {(const float*)d_in[8],  (const float*)d_in[14], (const float*)d_in[20], (const float*)d_in[26]};
    const float* g_wr[4]  = {(const float*)d_in[9],  (const float*)d_in[15], (const float*)d_in[21], (const float*)d_in[27]};
    const float* g_br[4]  = {(const float*)d_in[10], (const float*)d_in[16], (const float*)d_in[22], (const float*)d_in[28]};
    const float* g_att[4] = {(const float*)d_in[11], (const float*)d_in[17], (const float*)d_in[23], (const float*)d_in[29]};
    const float* g_b[4]   = {(const float*)d_in[12], (const float*)d_in[18], (const float*)d_in[24], (const float*)d_in[30]};
    const float* lab_w = (const float*)d_in[31];
    const float* lab_b = (const float*)d_in[32];
    const float* val_w = (const float*)d_in[33];
    const float* val_b = (const float*)d_in[34];
    const float* skw   = (const float*)d_in[35];
    const float* skb   = (const float*)d_in[36];

    float* out = (float*)d_out;
    float* o0 = out;            // batch[:,:,:4]   32768
    float* o1 = out + 32768;    // batch[:,:,4:5]   8192
    float* o2 = out + 40960;    // logits          32768
    float* o3 = out + 73728;    // values           8192
    float* o4 = out + 81920;    // latent          24576  (doubles as latf)
    float* o5 = out + 106496;   // adj           1048576
    float* o6 = out + 1155072;  // edge_dist     1048576

    // Scratch: 6.25 MB (xA/xB and f32 hl/hr eliminated by fusion).
    char* p = (char*)d_ws;
    auto carve = [&](size_t bytes) { void* r = (void*)p; p += (bytes + 255) & ~(size_t)255; return r; };
    double*   aos  = (double*)  carve((size_t)BB * NN * 4 * 8);   // 256 KB
    unsigned* hl2p = (unsigned*)carve((size_t)BB * NN * 32 * 4);  // 1 MB
    unsigned* hr2p = (unsigned*)carve((size_t)BB * NN * 32 * 4);
    unsigned* hl3p = (unsigned*)carve((size_t)BB * NN * 32 * 4);
    unsigned* hr3p = (unsigned*)carve((size_t)BB * NN * 32 * 4);
    unsigned* hl4p = (unsigned*)carve((size_t)BB * NN * 32 * 4);
    unsigned* hr4p = (unsigned*)carve((size_t)BB * NN * 32 * 4);

    enc_kernel<<<dim3(BB, 4), 256, 0, stream>>>(batch, enc_w1, enc_b1, enc_w2, enc_b2,
                                                enc_w3, enc_b3, aos, o0, o1, o4, o5);
    gabriel_kernel<<<dim3(32, BB), 256, 0, stream>>>(aos, o5, o6);

    // layer 1 (lin1 + lin2 fused) -> hl2p/hr2p
    attnA_kernel<<<BB * 16, 256, 0, stream>>>(o4,
        g_wl[0], g_bl[0], g_wr[0], g_br[0], g_att[0], g_b[0], o5,
        g_wl[1], g_bl[1], g_wr[1], g_br[1], hl2p, hr2p);
    // layer 2 (lin3 + lin4 fused) -> hl3p/hr3p/hl4p/hr4p
    attnB_kernel<<<BB * 16, 256, 0, stream>>>(hl2p, hr2p,
        g_att[1], g_b[1], o5,
        g_wl[2], g_bl[2], g_wr[2], g_br[2],
        g_wl[3], g_bl[3], g_wr[3], g_br[3],
        hl3p, hr3p, hl4p, hr4p);
    // layers 3 + 4 with skip + heads -> o2/o3
    attnCD_kernel<<<dim3(BB * 16, 2), 256, 0, stream>>>(hl3p, hr3p, hl4p, hr4p,
        g_att[2], g_b[2], g_att[3], g_b[3], o5, o4, skw, skb,
        lab_w, lab_b, o2, val_w, val_b, o3);
}